// Round 5
// baseline (778.593 us; speedup 1.0000x reference)
//
#include <hip/hip_runtime.h>
#include <cstdint>
#include <cstddef>

#define B_   8
#define S_   2048
#define H_   1024
#define K3_  3072              // 3*H
#define SC_  512               // time-chunk length
#define MC_  (B_ * SC_)        // 4096 rows per GEMM chunk
#define NCH_ (S_ / SC_)        // 4 chunks
#define WIN_ 32                // scan LDS window (steps)
#define WSCALE 32.0f           // pre-scale W so f16 lo-plane stays normal-range

typedef __attribute__((ext_vector_type(8))) _Float16 f16x8;
typedef __attribute__((ext_vector_type(4))) _Float16 f16x4;
typedef __attribute__((ext_vector_type(4))) float f32x4;

// --------------------------------------------- cast x time-slice -> f16 hi/lo (chunk-local rows)
__global__ __launch_bounds__(256) void castx_kernel(const float4* __restrict__ X,
                                                    f16x4* __restrict__ Xh,
                                                    f16x4* __restrict__ Xl, int s0) {
    int i = blockIdx.x * 256 + threadIdx.x;        // float4 index in chunk, [0, 4096*256)
    int r  = i >> 8;                               // chunk row
    int c4 = i & 255;                              // float4 within row
    int b  = r >> 9;
    int sl = r & (SC_ - 1);
    size_t src = ((size_t)b * S_ + s0 + sl) * (H_ / 4) + c4;
    float4 v = ((const float4*)X)[src];
    _Float16 h0 = (_Float16)v.x, h1 = (_Float16)v.y, h2 = (_Float16)v.z, h3 = (_Float16)v.w;
    f16x4 hv = {h0, h1, h2, h3};
    f16x4 lv = {(_Float16)(v.x - (float)h0), (_Float16)(v.y - (float)h1),
                (_Float16)(v.z - (float)h2), (_Float16)(v.w - (float)h3)};
    Xh[i] = hv;
    Xl[i] = lv;
}

// ------------------------- transpose + scale + split W [H,3H] fp32 -> Wt hi/lo [3H,H] f16
__global__ __launch_bounds__(256) void transW_kernel(const float* __restrict__ W,
                                                     _Float16* __restrict__ Wth,
                                                     _Float16* __restrict__ Wtl) {
    __shared__ float tile[32][33];
    int bc  = blockIdx.x * 32;
    int brr = blockIdx.y * 32;
    int tx = threadIdx.x & 31;
    int ty = threadIdx.x >> 5;
#pragma unroll
    for (int i = 0; i < 4; ++i) {
        int r = ty + i * 8;
        tile[r][tx] = W[(size_t)(brr + r) * K3_ + bc + tx];
    }
    __syncthreads();
#pragma unroll
    for (int i = 0; i < 4; ++i) {
        int r = ty + i * 8;            // row in Wt tile = col in W
        float v = tile[tx][r] * WSCALE;
        _Float16 h = (_Float16)v;
        _Float16 l = (_Float16)(v - (float)h);
        Wth[(size_t)(bc + r) * H_ + brr + tx] = h;
        Wtl[(size_t)(bc + r) * H_ + brr + tx] = l;
    }
}

// ---------------------------------------------------------------- split-f16 MFMA GEMM (one chunk)
// U[m,n] = (1/WSCALE) * sum_k (Ah+Al)[m,k]*(Bh+Bl)[n,k], 3-term: AhBh + AhBl + AlBh
__global__ __launch_bounds__(256) void gemm_kernel(const _Float16* __restrict__ Ah,
                                                   const _Float16* __restrict__ Al,
                                                   const _Float16* __restrict__ Bh,
                                                   const _Float16* __restrict__ Bl,
                                                   float* __restrict__ C) {
    __shared__ _Float16 Ahs[128 * 32];
    __shared__ _Float16 Als[128 * 32];
    __shared__ _Float16 Bhs[128 * 32];
    __shared__ _Float16 Bls[128 * 32];
    const int tid  = threadIdx.x;
    const int lane = tid & 63;
    const int w    = tid >> 6;
    const int wm   = (w >> 1) * 64;
    const int wn   = (w & 1) * 64;
    const int bm   = blockIdx.y * 128;
    const int bn   = blockIdx.x * 128;
    const int K    = 1024;

    f32x4 acc[4][4];
#pragma unroll
    for (int i = 0; i < 4; ++i)
#pragma unroll
        for (int j = 0; j < 4; ++j) {
            f32x4 z = {0.f, 0.f, 0.f, 0.f};
            acc[i][j] = z;
        }

    const int quad = lane >> 4;
    const int lrow = lane & 15;

    for (int kk = 0; kk < K; kk += 32) {
#pragma unroll
        for (int j = 0; j < 2; ++j) {
            int idx = j * 256 + tid;          // 0..511
            int row = idx >> 2;
            int kp  = (idx & 3) << 3;
            size_t aoff = (size_t)(bm + row) * K + kk + kp;
            size_t boff = (size_t)(bn + row) * K + kk + kp;
            unsigned base = (unsigned)(j * 256 + (tid & ~63)) * 16u;  // wave-uniform bytes
            __builtin_amdgcn_global_load_lds(
                (const __attribute__((address_space(1))) void*)(Ah + aoff),
                (__attribute__((address_space(3))) void*)((char*)Ahs + base), 16, 0, 0);
            __builtin_amdgcn_global_load_lds(
                (const __attribute__((address_space(1))) void*)(Al + aoff),
                (__attribute__((address_space(3))) void*)((char*)Als + base), 16, 0, 0);
            __builtin_amdgcn_global_load_lds(
                (const __attribute__((address_space(1))) void*)(Bh + boff),
                (__attribute__((address_space(3))) void*)((char*)Bhs + base), 16, 0, 0);
            __builtin_amdgcn_global_load_lds(
                (const __attribute__((address_space(1))) void*)(Bl + boff),
                (__attribute__((address_space(3))) void*)((char*)Bls + base), 16, 0, 0);
        }
        __syncthreads();

        f16x8 ah[4], al[4], bh[4], bl[4];
#pragma unroll
        for (int i = 0; i < 4; ++i) {
            ah[i] = *(const f16x8*)(Ahs + (wm + i * 16 + lrow) * 32 + quad * 8);
            al[i] = *(const f16x8*)(Als + (wm + i * 16 + lrow) * 32 + quad * 8);
        }
#pragma unroll
        for (int j = 0; j < 4; ++j) {
            bh[j] = *(const f16x8*)(Bhs + (wn + j * 16 + lrow) * 32 + quad * 8);
            bl[j] = *(const f16x8*)(Bls + (wn + j * 16 + lrow) * 32 + quad * 8);
        }

#pragma unroll
        for (int i = 0; i < 4; ++i)
#pragma unroll
            for (int j = 0; j < 4; ++j) {
                acc[i][j] = __builtin_amdgcn_mfma_f32_16x16x32_f16(al[i], bh[j], acc[i][j], 0, 0, 0);
                acc[i][j] = __builtin_amdgcn_mfma_f32_16x16x32_f16(ah[i], bl[j], acc[i][j], 0, 0, 0);
                acc[i][j] = __builtin_amdgcn_mfma_f32_16x16x32_f16(ah[i], bh[j], acc[i][j], 0, 0, 0);
            }
        __syncthreads();
    }

    const float inv = 1.0f / WSCALE;
#pragma unroll
    for (int i = 0; i < 4; ++i)
#pragma unroll
        for (int j = 0; j < 4; ++j)
#pragma unroll
            for (int r = 0; r < 4; ++r) {
                int row = bm + wm + i * 16 + quad * 4 + r;
                int col = bn + wn + j * 16 + lrow;
                C[(size_t)row * K3_ + col] = acc[i][j][r] * inv;
            }
}

// ---------------------------------------------------------------- producer-consumer scan
// Block = 256 threads (4 waves): wave 0 computes 64 channels; waves 1-3 stream U/x rows
// into a double-buffered LDS ring via global_load_lds (width 4: LDS dest = base + lane*4,
// exactly one 64-channel row). Loader waves own the vmcnt debt; __syncthreads is the handoff.
__global__ __launch_bounds__(256, 1) void scan_kernel(const float* __restrict__ U,
                                                      const float* __restrict__ X,
                                                      const float* __restrict__ vf,
                                                      const float* __restrict__ vr,
                                                      const float* __restrict__ bfv,
                                                      const float* __restrict__ brv,
                                                      float* __restrict__ Y,
                                                      float* __restrict__ Cf,
                                                      float* __restrict__ carry,
                                                      int s0, int last) {
    __shared__ float ring[2][WIN_][4][64];   // [buf][step][stream f/c/r/x][ch] = 64 KB
    const int tid  = threadIdx.x;
    const int lane = tid & 63;
    const int wid  = tid >> 6;
    const int bi   = blockIdx.x;             // 0..127
    const int gid0 = bi * 64;                // first channel of this block
    const int b    = gid0 >> 10;             // 16 blocks per batch row -> uniform b
    const int h0   = gid0 & 1023;

    const float* Ubase = U + (size_t)b * SC_ * K3_ + h0;        // + t*K3_ + s*H_ + lane
    const float* Xbase = X + ((size_t)b * S_ + s0) * H_ + h0;   // + t*H_ + lane
    float*       Ybase = Y + ((size_t)b * S_ + s0) * H_ + h0;

    const float vfh = vf[h0 + lane], vrh = vr[h0 + lane];
    const float bfh = bfv[h0 + lane], brh = brv[h0 + lane];
    float c = (s0 == 0) ? 0.f : carry[gid0 + lane];

    auto load_window = [&](int t0, int buf) {
        // 128 rows (32 steps x 4 streams) split over loader waves 1..3
        for (int idx = wid - 1; idx < WIN_ * 4; idx += 3) {
            int t = idx >> 2;
            int s = idx & 3;
            const float* gp = (s < 3)
                ? Ubase + (size_t)(t0 + t) * K3_ + s * H_ + lane
                : Xbase + (size_t)(t0 + t) * H_ + lane;
            unsigned loff = (unsigned)(((buf * WIN_ + t) * 4 + s) * 64) * 4u;  // wave-uniform
            __builtin_amdgcn_global_load_lds(
                (const __attribute__((address_space(1))) void*)gp,
                (__attribute__((address_space(3))) void*)((char*)&ring[0][0][0][0] + loff), 4, 0, 0);
        }
    };

    if (wid) load_window(0, 0);
    __syncthreads();

    const int NW = SC_ / WIN_;               // 16 windows
    for (int w = 0; w < NW; ++w) {
        const int buf = w & 1;
        if (wid) {
            if (w + 1 < NW) load_window((w + 1) * WIN_, buf ^ 1);
        } else {
            const int t0 = w * WIN_;
#pragma unroll 8
            for (int t = 0; t < WIN_; ++t) {
                float zf = ring[buf][t][0][lane];
                float xc = ring[buf][t][1][lane];
                float zr = ring[buf][t][2][lane];
                float xv = ring[buf][t][3][lane];
                zf += bfh + vfh * c;
                zr += brh + vrh * c;
                float ft = __builtin_amdgcn_rcpf(1.f + __expf(-zf));
                float rt = __builtin_amdgcn_rcpf(1.f + __expf(-zr));
                c = ft * (c - xc) + xc;
                float ht = rt * (c - xv) + xv;
                Ybase[(size_t)(t0 + t) * H_ + lane] = ht;
            }
        }
        __syncthreads();
    }

    if (wid == 0) {
        carry[gid0 + lane] = c;
        if (last) Cf[(size_t)b * H_ + h0 + lane] = c;
    }
}

// ---------------------------------------------------------------- launcher
extern "C" void kernel_launch(void* const* d_in, const int* in_sizes, int n_in,
                              void* d_out, int out_size, void* d_ws, size_t ws_size,
                              hipStream_t stream) {
    const float* x  = (const float*)d_in[0];
    const float* W  = (const float*)d_in[1];
    const float* vf = (const float*)d_in[2];
    const float* vr = (const float*)d_in[3];
    const float* bf = (const float*)d_in[4];
    const float* br = (const float*)d_in[5];
    float* y  = (float*)d_out;
    float* cf = y + (size_t)B_ * S_ * H_;

    // ws layout: U_c fp32 50.3MB | xh 8.4MB | xl 8.4MB | Wth 6.3MB | Wtl 6.3MB | carry 32KB  => ~79.8MB
    float* U = (float*)d_ws;
    _Float16* xh  = (_Float16*)(U + (size_t)MC_ * K3_);
    _Float16* xl  = xh + (size_t)MC_ * H_;
    _Float16* Wth = xl + (size_t)MC_ * H_;
    _Float16* Wtl = Wth + (size_t)K3_ * H_;
    float* carry  = (float*)(Wtl + (size_t)K3_ * H_);

    transW_kernel<<<dim3(K3_ / 32, H_ / 32), 256, 0, stream>>>(W, Wth, Wtl);
    for (int ci = 0; ci < NCH_; ++ci) {
        int s0 = ci * SC_;
        castx_kernel<<<(MC_ * H_ / 4) / 256, 256, 0, stream>>>((const float4*)x, (f16x4*)xh, (f16x4*)xl, s0);
        gemm_kernel<<<dim3(K3_ / 128, MC_ / 128), 256, 0, stream>>>(xh, xl, Wth, Wtl, U);
        scan_kernel<<<B_ * H_ / 64, 256, 0, stream>>>(U, x, vf, vr, bf, br, y, cf, carry,
                                                      s0, ci == NCH_ - 1 ? 1 : 0);
    }
}

// Round 6
// 596.532 us; speedup vs baseline: 1.3052x; 1.3052x over previous
//
#include <hip/hip_runtime.h>
#include <cstdint>
#include <cstddef>

#define B_   8
#define S_   2048
#define H_   1024
#define K3_  3072              // 3*H
#define SC_  512               // time-chunk length
#define MC_  (B_ * SC_)        // 4096 rows per GEMM chunk
#define NCH_ 4                 // chunks
#define NSB_ 32                // scan blocks inside fused launch (32*256 = 8192 channels)
#define WSCALE 32.0f           // pre-scale W so f16 lo-plane stays normal-range

typedef __attribute__((ext_vector_type(8))) _Float16 f16x8;
typedef __attribute__((ext_vector_type(4))) _Float16 f16x4;
typedef __attribute__((ext_vector_type(4))) float f32x4;

// --------------------------------------------- cast x time-slice -> f16 hi/lo (chunk-local rows)
__global__ __launch_bounds__(256) void castx_kernel(const float4* __restrict__ X,
                                                    f16x4* __restrict__ Xh,
                                                    f16x4* __restrict__ Xl, int s0) {
    int i = blockIdx.x * 256 + threadIdx.x;        // float4 index in chunk, [0, 4096*256)
    int r  = i >> 8;                               // chunk row
    int c4 = i & 255;                              // float4 within row
    int b  = r >> 9;
    int sl = r & (SC_ - 1);
    size_t src = ((size_t)b * S_ + s0 + sl) * (H_ / 4) + c4;
    float4 v = ((const float4*)X)[src];
    _Float16 h0 = (_Float16)v.x, h1 = (_Float16)v.y, h2 = (_Float16)v.z, h3 = (_Float16)v.w;
    f16x4 hv = {h0, h1, h2, h3};
    f16x4 lv = {(_Float16)(v.x - (float)h0), (_Float16)(v.y - (float)h1),
                (_Float16)(v.z - (float)h2), (_Float16)(v.w - (float)h3)};
    Xh[i] = hv;
    Xl[i] = lv;
}

// ------------------------- transpose + scale + split W [H,3H] fp32 -> Wt hi/lo [3H,H] f16
__global__ __launch_bounds__(256) void transW_kernel(const float* __restrict__ W,
                                                     _Float16* __restrict__ Wth,
                                                     _Float16* __restrict__ Wtl) {
    __shared__ float tile[32][33];
    int bc  = blockIdx.x * 32;
    int brr = blockIdx.y * 32;
    int tx = threadIdx.x & 31;
    int ty = threadIdx.x >> 5;
#pragma unroll
    for (int i = 0; i < 4; ++i) {
        int r = ty + i * 8;
        tile[r][tx] = W[(size_t)(brr + r) * K3_ + bc + tx];
    }
    __syncthreads();
#pragma unroll
    for (int i = 0; i < 4; ++i) {
        int r = ty + i * 8;            // row in Wt tile = col in W
        float v = tile[tx][r] * WSCALE;
        _Float16 h = (_Float16)v;
        _Float16 l = (_Float16)(v - (float)h);
        Wth[(size_t)(bc + r) * H_ + brr + tx] = h;
        Wtl[(size_t)(bc + r) * H_ + brr + tx] = l;
    }
}

// ---------------------------------------------------------------- fused GEMM + scan
// Blocks [0, nScan): scan chunk (s0scan) from Uprev — one channel per thread, waves
// independent, no barriers. Blocks [nScan, nScan+768): split-f16 3-term MFMA GEMM
// writing C (= U buffer for the *current* chunk). The two paths share nothing; ordering
// with producers/consumers comes from launch boundaries.
__global__ __launch_bounds__(256) void fused_kernel(
        const _Float16* __restrict__ Ah, const _Float16* __restrict__ Al,
        const _Float16* __restrict__ Bh, const _Float16* __restrict__ Bl,
        float* __restrict__ C,
        const float* __restrict__ Uprev, const float* __restrict__ X,
        const float* __restrict__ vf,  const float* __restrict__ vr,
        const float* __restrict__ bfv, const float* __restrict__ brv,
        float* __restrict__ Y, float* __restrict__ carry,
        int s0scan, int nScan) {
    __shared__ _Float16 Ahs[128 * 32];
    __shared__ _Float16 Als[128 * 32];
    __shared__ _Float16 Bhs[128 * 32];
    __shared__ _Float16 Bls[128 * 32];

    if ((int)blockIdx.x < nScan) {
        // ---------------- scan path (chunk s0scan/SC_), hidden under the GEMM ----------------
        int gid = blockIdx.x * 256 + threadIdx.x;   // 0..8191 channel
        int b = gid >> 10;
        int h = gid & 1023;
        float vfh = vf[h], vrh = vr[h], bfh = bfv[h], brh = brv[h];
        const float* Ub = Uprev + (size_t)b * SC_ * K3_ + h;
        const float* Xb = X + ((size_t)b * S_ + s0scan) * H_ + h;
        float* Yb = Y + ((size_t)b * S_ + s0scan) * H_ + h;
        float c = (s0scan == 0) ? 0.f : carry[gid];

        float Af[8], Ac[8], Ar[8], Ax[8];
        float Bf[8], Bc[8], Br[8], Bx[8];
        auto LOAD = [&](int t0, float (&sf)[8], float (&sc)[8], float (&sr)[8], float (&sx)[8]) {
#pragma unroll
            for (int u = 0; u < 8; ++u) {
                size_t o = (size_t)(t0 + u) * K3_;
                sf[u] = Ub[o];
                sc[u] = Ub[o + H_];
                sr[u] = Ub[o + 2 * H_];
                sx[u] = Xb[(size_t)(t0 + u) * H_];
            }
        };
        auto COMP = [&](int t0, float (&sf)[8], float (&sc)[8], float (&sr)[8], float (&sx)[8]) {
#pragma unroll
            for (int u = 0; u < 8; ++u) {
                float zf = sf[u] + bfh + vfh * c;
                float zr = sr[u] + brh + vrh * c;
                float xc = sc[u];
                float ft = __builtin_amdgcn_rcpf(1.f + __expf(-zf));
                float rt = __builtin_amdgcn_rcpf(1.f + __expf(-zr));
                c = ft * (c - xc) + xc;
                float xv = sx[u];
                float ht = rt * (c - xv) + xv;
                Yb[(size_t)(t0 + u) * H_] = ht;
            }
        };
        LOAD(0, Af, Ac, Ar, Ax);
        for (int t0 = 0; t0 < SC_; t0 += 16) {
            LOAD(t0 + 8, Bf, Bc, Br, Bx);
            COMP(t0, Af, Ac, Ar, Ax);
            if (t0 + 16 < SC_) LOAD(t0 + 16, Af, Ac, Ar, Ax);
            COMP(t0 + 8, Bf, Bc, Br, Bx);
        }
        carry[gid] = c;
        return;
    }

    // ---------------- GEMM path: U[m,n] = (1/WSCALE) * (AhBh + AhBl + AlBh) ----------------
    const int idxb = (int)blockIdx.x - nScan;       // 0..767
    const int bm   = (idxb / 24) * 128;
    const int bn   = (idxb % 24) * 128;
    const int tid  = threadIdx.x;
    const int lane = tid & 63;
    const int w    = tid >> 6;
    const int wm   = (w >> 1) * 64;
    const int wn   = (w & 1) * 64;
    const int K    = 1024;

    f32x4 acc[4][4];
#pragma unroll
    for (int i = 0; i < 4; ++i)
#pragma unroll
        for (int j = 0; j < 4; ++j) {
            f32x4 z = {0.f, 0.f, 0.f, 0.f};
            acc[i][j] = z;
        }

    const int quad = lane >> 4;
    const int lrow = lane & 15;

    for (int kk = 0; kk < K; kk += 32) {
#pragma unroll
        for (int j = 0; j < 2; ++j) {
            int idx = j * 256 + tid;          // 0..511
            int row = idx >> 2;
            int kp  = (idx & 3) << 3;
            size_t aoff = (size_t)(bm + row) * K + kk + kp;
            size_t boff = (size_t)(bn + row) * K + kk + kp;
            unsigned base = (unsigned)(j * 256 + (tid & ~63)) * 16u;  // wave-uniform bytes
            __builtin_amdgcn_global_load_lds(
                (const __attribute__((address_space(1))) void*)(Ah + aoff),
                (__attribute__((address_space(3))) void*)((char*)Ahs + base), 16, 0, 0);
            __builtin_amdgcn_global_load_lds(
                (const __attribute__((address_space(1))) void*)(Al + aoff),
                (__attribute__((address_space(3))) void*)((char*)Als + base), 16, 0, 0);
            __builtin_amdgcn_global_load_lds(
                (const __attribute__((address_space(1))) void*)(Bh + boff),
                (__attribute__((address_space(3))) void*)((char*)Bhs + base), 16, 0, 0);
            __builtin_amdgcn_global_load_lds(
                (const __attribute__((address_space(1))) void*)(Bl + boff),
                (__attribute__((address_space(3))) void*)((char*)Bls + base), 16, 0, 0);
        }
        __syncthreads();

        f16x8 ah[4], al[4], bh[4], bl[4];
#pragma unroll
        for (int i = 0; i < 4; ++i) {
            ah[i] = *(const f16x8*)(Ahs + (wm + i * 16 + lrow) * 32 + quad * 8);
            al[i] = *(const f16x8*)(Als + (wm + i * 16 + lrow) * 32 + quad * 8);
        }
#pragma unroll
        for (int j = 0; j < 4; ++j) {
            bh[j] = *(const f16x8*)(Bhs + (wn + j * 16 + lrow) * 32 + quad * 8);
            bl[j] = *(const f16x8*)(Bls + (wn + j * 16 + lrow) * 32 + quad * 8);
        }

#pragma unroll
        for (int i = 0; i < 4; ++i)
#pragma unroll
            for (int j = 0; j < 4; ++j) {
                acc[i][j] = __builtin_amdgcn_mfma_f32_16x16x32_f16(al[i], bh[j], acc[i][j], 0, 0, 0);
                acc[i][j] = __builtin_amdgcn_mfma_f32_16x16x32_f16(ah[i], bl[j], acc[i][j], 0, 0, 0);
                acc[i][j] = __builtin_amdgcn_mfma_f32_16x16x32_f16(ah[i], bh[j], acc[i][j], 0, 0, 0);
            }
        __syncthreads();
    }

    const float inv = 1.0f / WSCALE;
#pragma unroll
    for (int i = 0; i < 4; ++i)
#pragma unroll
        for (int j = 0; j < 4; ++j)
#pragma unroll
            for (int r = 0; r < 4; ++r) {
                int row = bm + wm + i * 16 + quad * 4 + r;
                int col = bn + wn + j * 16 + lrow;
                C[(size_t)row * K3_ + col] = acc[i][j][r] * inv;
            }
}

// ---------------------------------------------------------------- standalone scan (final chunk)
// R4-proven: 4 rolling 8-step register buffers, one wave per block.
__global__ __launch_bounds__(64, 1) void scan_kernel(const float* __restrict__ U,
                                                     const float* __restrict__ X,
                                                     const float* __restrict__ vf,
                                                     const float* __restrict__ vr,
                                                     const float* __restrict__ bfv,
                                                     const float* __restrict__ brv,
                                                     float* __restrict__ Y,
                                                     float* __restrict__ Cf,
                                                     float* __restrict__ carry,
                                                     int s0) {
    int gid = blockIdx.x * 64 + threadIdx.x;   // 0..8191
    int b = gid >> 10;
    int h = gid & 1023;
    float vfh = vf[h], vrh = vr[h], bfh = bfv[h], brh = brv[h];
    const float* Ub = U + (size_t)b * SC_ * K3_ + h;
    const float* Xb = X + ((size_t)b * S_ + s0) * H_ + h;
    float* Yb = Y + ((size_t)b * S_ + s0) * H_ + h;
    float c = carry[gid];

    float Af[8], Ac[8], Ar[8], Ax[8];
    float Bf[8], Bc[8], Br[8], Bx[8];
    float Cg[8], Cc[8], Cr[8], Cx[8];
    float Df[8], Dc[8], Dr[8], Dx[8];

    auto LOAD = [&](int t0, float (&sf)[8], float (&sc)[8], float (&sr)[8], float (&sx)[8]) {
#pragma unroll
        for (int u = 0; u < 8; ++u) {
            size_t o = (size_t)(t0 + u) * K3_;
            sf[u] = Ub[o];
            sc[u] = Ub[o + H_];
            sr[u] = Ub[o + 2 * H_];
            sx[u] = Xb[(size_t)(t0 + u) * H_];
        }
    };
    auto COMP = [&](int t0, float (&sf)[8], float (&sc)[8], float (&sr)[8], float (&sx)[8]) {
#pragma unroll
        for (int u = 0; u < 8; ++u) {
            float zf = sf[u] + bfh + vfh * c;
            float zr = sr[u] + brh + vrh * c;
            float xc = sc[u];
            float ft = __builtin_amdgcn_rcpf(1.f + __expf(-zf));
            float rt = __builtin_amdgcn_rcpf(1.f + __expf(-zr));
            c = ft * (c - xc) + xc;
            float xv = sx[u];
            float ht = rt * (c - xv) + xv;
            Yb[(size_t)(t0 + u) * H_] = ht;
        }
    };

    LOAD(0, Af, Ac, Ar, Ax);
    LOAD(8, Bf, Bc, Br, Bx);
    LOAD(16, Cg, Cc, Cr, Cx);
    for (int t0 = 0; t0 < SC_; t0 += 32) {
        LOAD(t0 + 24, Df, Dc, Dr, Dx);
        COMP(t0, Af, Ac, Ar, Ax);
        if (t0 + 32 < SC_) LOAD(t0 + 32, Af, Ac, Ar, Ax);
        COMP(t0 + 8, Bf, Bc, Br, Bx);
        if (t0 + 40 < SC_) LOAD(t0 + 40, Bf, Bc, Br, Bx);
        COMP(t0 + 16, Cg, Cc, Cr, Cx);
        if (t0 + 48 < SC_) LOAD(t0 + 48, Cg, Cc, Cr, Cx);
        COMP(t0 + 24, Df, Dc, Dr, Dx);
    }
    Cf[(size_t)b * H_ + h] = c;
}

// ---------------------------------------------------------------- launcher
extern "C" void kernel_launch(void* const* d_in, const int* in_sizes, int n_in,
                              void* d_out, int out_size, void* d_ws, size_t ws_size,
                              hipStream_t stream) {
    const float* x  = (const float*)d_in[0];
    const float* W  = (const float*)d_in[1];
    const float* vf = (const float*)d_in[2];
    const float* vr = (const float*)d_in[3];
    const float* bf = (const float*)d_in[4];
    const float* br = (const float*)d_in[5];
    float* y  = (float*)d_out;
    float* cf = y + (size_t)B_ * S_ * H_;

    // ws layout: U0 50.3MB | U1 50.3MB | xh 8.4MB | xl 8.4MB | Wth 6.3MB | Wtl 6.3MB | carry 32KB
    // total ~130.1MB  (<= proven-safe 134MB from R1)
    float* U0 = (float*)d_ws;
    float* U1 = U0 + (size_t)MC_ * K3_;
    _Float16* xh  = (_Float16*)(U1 + (size_t)MC_ * K3_);
    _Float16* xl  = xh + (size_t)MC_ * H_;
    _Float16* Wth = xl + (size_t)MC_ * H_;
    _Float16* Wtl = Wth + (size_t)K3_ * H_;
    float* carry  = (float*)(Wtl + (size_t)K3_ * H_);
    float* Ubuf[2] = {U0, U1};

    transW_kernel<<<dim3(K3_ / 32, H_ / 32), 256, 0, stream>>>(W, Wth, Wtl);

    // chunk 0: GEMM only (nScan = 0)
    castx_kernel<<<(MC_ * H_ / 4) / 256, 256, 0, stream>>>((const float4*)x, (f16x4*)xh, (f16x4*)xl, 0);
    fused_kernel<<<768, 256, 0, stream>>>(xh, xl, Wth, Wtl, Ubuf[0],
                                          Ubuf[0], x, vf, vr, bf, br, y, carry, 0, 0);

    // chunks 1..3: GEMM(i) fused with scan(i-1)
    for (int ci = 1; ci < NCH_; ++ci) {
        castx_kernel<<<(MC_ * H_ / 4) / 256, 256, 0, stream>>>((const float4*)x, (f16x4*)xh, (f16x4*)xl, ci * SC_);
        fused_kernel<<<768 + NSB_, 256, 0, stream>>>(xh, xl, Wth, Wtl, Ubuf[ci & 1],
                                                     Ubuf[(ci - 1) & 1], x, vf, vr, bf, br, y, carry,
                                                     (ci - 1) * SC_, NSB_);
    }

    // final scan: chunk 3
    scan_kernel<<<B_ * H_ / 64, 64, 0, stream>>>(Ubuf[1], x, vf, vr, bf, br, y, cf, carry, 3 * SC_);
}

// Round 7
// 575.352 us; speedup vs baseline: 1.3532x; 1.0368x over previous
//
#include <hip/hip_runtime.h>
#include <cstdint>
#include <cstddef>

#define B_   8
#define S_   2048
#define H_   1024
#define K3_  3072              // 3*H
#define WSCALE 32.0f           // pre-scale W so f16 lo-plane stays normal-range

typedef __attribute__((ext_vector_type(8))) _Float16 f16x8;
typedef __attribute__((ext_vector_type(4))) _Float16 f16x4;
typedef __attribute__((ext_vector_type(4))) float f32x4;

// --------------------------------------------- cast body: x time-slice -> f16 hi/lo planes
// coarse: each thread converts 4 float4s (grid-stride within the cast range)
__device__ __forceinline__ void cast_body(const float4* __restrict__ X,
                                          f16x4* __restrict__ Xh, f16x4* __restrict__ Xl,
                                          int ci, int tid, int lcl, int s0) {
    const int len  = 1 << lcl;
    const int nthr = (B_ * len * H_) >> 4;     // threads in cast range (4 float4 each)
    int i0 = ci * 256 + tid;
#pragma unroll
    for (int u = 0; u < 4; ++u) {
        int i  = i0 + u * nthr;
        int r  = i >> 8;                       // chunk-local row
        int c4 = i & 255;
        int b  = r >> lcl;
        int sl = r & (len - 1);
        size_t src = ((size_t)b * S_ + s0 + sl) * (H_ / 4) + c4;
        float4 v = X[src];
        _Float16 h0 = (_Float16)v.x, h1 = (_Float16)v.y, h2 = (_Float16)v.z, h3 = (_Float16)v.w;
        f16x4 hv = {h0, h1, h2, h3};
        f16x4 lv = {(_Float16)(v.x - (float)h0), (_Float16)(v.y - (float)h1),
                    (_Float16)(v.z - (float)h2), (_Float16)(v.w - (float)h3)};
        size_t dst = ((size_t)b * len + sl) * (H_ / 4) + c4;
        Xh[dst] = hv;
        Xl[dst] = lv;
    }
}

// --------------------------------------------- standalone cast (fallback path)
__global__ __launch_bounds__(256) void castx_kernel(const float4* __restrict__ X,
                                                    f16x4* __restrict__ Xh,
                                                    f16x4* __restrict__ Xl,
                                                    int lcl, int s0) {
    cast_body(X, Xh, Xl, blockIdx.x, threadIdx.x, lcl, s0);
}

// --------------------------------------------- prep: transW (blocks 0..3071) + cast chunk0
__global__ __launch_bounds__(256) void prep_kernel(const float* __restrict__ W,
                                                   _Float16* __restrict__ Wth,
                                                   _Float16* __restrict__ Wtl,
                                                   const float4* __restrict__ X,
                                                   f16x4* __restrict__ Xh,
                                                   f16x4* __restrict__ Xl) {
    __shared__ float tile[32][33];
    if ((int)blockIdx.x < 3072) {
        int idx = blockIdx.x;
        int bc  = (idx % 96) * 32;         // col block in W (N dim)
        int brr = (idx / 96) * 32;         // row block in W (K dim)
        int tx = threadIdx.x & 31;
        int ty = threadIdx.x >> 5;
#pragma unroll
        for (int i = 0; i < 4; ++i) {
            int r = ty + i * 8;
            tile[r][tx] = W[(size_t)(brr + r) * K3_ + bc + tx];
        }
        __syncthreads();
#pragma unroll
        for (int i = 0; i < 4; ++i) {
            int r = ty + i * 8;            // row in Wt tile = col in W
            float v = tile[tx][r] * WSCALE;
            _Float16 h = (_Float16)v;
            _Float16 l = (_Float16)(v - (float)h);
            Wth[(size_t)(bc + r) * H_ + brr + tx] = h;
            Wtl[(size_t)(bc + r) * H_ + brr + tx] = l;
        }
    } else {
        cast_body((const float4*)X, Xh, Xl, (int)blockIdx.x - 3072, threadIdx.x, 9, 0);
    }
}

// ---------------------------------------------------------------- fused GEMM + scan + cast
// Blocks [0,nScan): scan of PREVIOUS chunk from Uprev (no barriers, waves independent).
// Blocks [nScan, nScan+nGemm): split-f16 3-term MFMA GEMM for CURRENT chunk -> C.
// Blocks [nScan+nGemm, +nCast): cast of NEXT chunk's x slice into the other x buffer.
// The three paths share nothing; ordering comes from launch boundaries.
__global__ __launch_bounds__(256) void fused_kernel(
        const _Float16* __restrict__ Ah, const _Float16* __restrict__ Al,
        const _Float16* __restrict__ Bh, const _Float16* __restrict__ Bl,
        float* __restrict__ C, int nGemm,
        const float* __restrict__ Uprev, int lenS, int s0scan, int nScan,
        const float* __restrict__ X,
        f16x4* __restrict__ Xch, f16x4* __restrict__ Xcl, int lclCast, int s0cast, int nCast,
        const float* __restrict__ vf,  const float* __restrict__ vr,
        const float* __restrict__ bfv, const float* __restrict__ brv,
        float* __restrict__ Y, float* __restrict__ carry) {
    __shared__ _Float16 Ahs[128 * 32];
    __shared__ _Float16 Als[128 * 32];
    __shared__ _Float16 Bhs[128 * 32];
    __shared__ _Float16 Bls[128 * 32];

    if ((int)blockIdx.x < nScan) {
        // ---------------- scan path (previous chunk), hidden under the GEMM ----------------
        int gid = blockIdx.x * 256 + threadIdx.x;   // 0..8191 channel
        int b = gid >> 10;
        int h = gid & 1023;
        float vfh = vf[h], vrh = vr[h], bfh = bfv[h], brh = brv[h];
        const float* Ub = Uprev + (size_t)b * lenS * K3_ + h;
        const float* Xb = X + ((size_t)b * S_ + s0scan) * H_ + h;
        float* Yb = Y + ((size_t)b * S_ + s0scan) * H_ + h;
        float c = (s0scan == 0) ? 0.f : carry[gid];

        float Af[8], Ac[8], Ar[8], Ax[8];
        float Bf[8], Bc[8], Br[8], Bx[8];
        auto LOAD = [&](int t0, float (&sf)[8], float (&sc)[8], float (&sr)[8], float (&sx)[8]) {
#pragma unroll
            for (int u = 0; u < 8; ++u) {
                size_t o = (size_t)(t0 + u) * K3_;
                sf[u] = Ub[o];
                sc[u] = Ub[o + H_];
                sr[u] = Ub[o + 2 * H_];
                sx[u] = Xb[(size_t)(t0 + u) * H_];
            }
        };
        auto COMP = [&](int t0, float (&sf)[8], float (&sc)[8], float (&sr)[8], float (&sx)[8]) {
#pragma unroll
            for (int u = 0; u < 8; ++u) {
                float zf = sf[u] + bfh + vfh * c;
                float zr = sr[u] + brh + vrh * c;
                float xc = sc[u];
                float ft = __builtin_amdgcn_rcpf(1.f + __expf(-zf));
                float rt = __builtin_amdgcn_rcpf(1.f + __expf(-zr));
                c = ft * (c - xc) + xc;
                float xv = sx[u];
                float ht = rt * (c - xv) + xv;
                Yb[(size_t)(t0 + u) * H_] = ht;
            }
        };
        LOAD(0, Af, Ac, Ar, Ax);
        for (int t0 = 0; t0 < lenS; t0 += 16) {
            LOAD(t0 + 8, Bf, Bc, Br, Bx);
            COMP(t0, Af, Ac, Ar, Ax);
            if (t0 + 16 < lenS) LOAD(t0 + 16, Af, Ac, Ar, Ax);
            COMP(t0 + 8, Bf, Bc, Br, Bx);
        }
        carry[gid] = c;
        return;
    }

    if ((int)blockIdx.x >= nScan + nGemm) {
        // ---------------- cast path (next chunk), hidden under the GEMM ----------------
        cast_body((const float4*)X, Xch, Xcl, (int)blockIdx.x - nScan - nGemm,
                  threadIdx.x, lclCast, s0cast);
        return;
    }

    // ---------------- GEMM path: U[m,n] = (1/WSCALE) * (AhBh + AhBl + AlBh) ----------------
    const int idxg = (int)blockIdx.x - nScan;
    const int bm   = (idxg / 24) * 128;
    const int bn   = (idxg % 24) * 128;
    const int tid  = threadIdx.x;
    const int lane = tid & 63;
    const int w    = tid >> 6;
    const int wm   = (w >> 1) * 64;
    const int wn   = (w & 1) * 64;
    const int K    = 1024;

    f32x4 acc[4][4];
#pragma unroll
    for (int i = 0; i < 4; ++i)
#pragma unroll
        for (int j = 0; j < 4; ++j) {
            f32x4 z = {0.f, 0.f, 0.f, 0.f};
            acc[i][j] = z;
        }

    const int quad = lane >> 4;
    const int lrow = lane & 15;

    for (int kk = 0; kk < K; kk += 32) {
#pragma unroll
        for (int j = 0; j < 2; ++j) {
            int idx = j * 256 + tid;          // 0..511
            int row = idx >> 2;
            int kp  = (idx & 3) << 3;
            size_t aoff = (size_t)(bm + row) * K + kk + kp;
            size_t boff = (size_t)(bn + row) * K + kk + kp;
            unsigned base = (unsigned)(j * 256 + (tid & ~63)) * 16u;  // wave-uniform bytes
            __builtin_amdgcn_global_load_lds(
                (const __attribute__((address_space(1))) void*)(Ah + aoff),
                (__attribute__((address_space(3))) void*)((char*)Ahs + base), 16, 0, 0);
            __builtin_amdgcn_global_load_lds(
                (const __attribute__((address_space(1))) void*)(Al + aoff),
                (__attribute__((address_space(3))) void*)((char*)Als + base), 16, 0, 0);
            __builtin_amdgcn_global_load_lds(
                (const __attribute__((address_space(1))) void*)(Bh + boff),
                (__attribute__((address_space(3))) void*)((char*)Bhs + base), 16, 0, 0);
            __builtin_amdgcn_global_load_lds(
                (const __attribute__((address_space(1))) void*)(Bl + boff),
                (__attribute__((address_space(3))) void*)((char*)Bls + base), 16, 0, 0);
        }
        __syncthreads();

        f16x8 ah[4], al[4], bh[4], bl[4];
#pragma unroll
        for (int i = 0; i < 4; ++i) {
            ah[i] = *(const f16x8*)(Ahs + (wm + i * 16 + lrow) * 32 + quad * 8);
            al[i] = *(const f16x8*)(Als + (wm + i * 16 + lrow) * 32 + quad * 8);
        }
#pragma unroll
        for (int j = 0; j < 4; ++j) {
            bh[j] = *(const f16x8*)(Bhs + (wn + j * 16 + lrow) * 32 + quad * 8);
            bl[j] = *(const f16x8*)(Bls + (wn + j * 16 + lrow) * 32 + quad * 8);
        }

#pragma unroll
        for (int i = 0; i < 4; ++i)
#pragma unroll
            for (int j = 0; j < 4; ++j) {
                acc[i][j] = __builtin_amdgcn_mfma_f32_16x16x32_f16(al[i], bh[j], acc[i][j], 0, 0, 0);
                acc[i][j] = __builtin_amdgcn_mfma_f32_16x16x32_f16(ah[i], bl[j], acc[i][j], 0, 0, 0);
                acc[i][j] = __builtin_amdgcn_mfma_f32_16x16x32_f16(ah[i], bh[j], acc[i][j], 0, 0, 0);
            }
        __syncthreads();
    }

    const float inv = 1.0f / WSCALE;
#pragma unroll
    for (int i = 0; i < 4; ++i)
#pragma unroll
        for (int j = 0; j < 4; ++j)
#pragma unroll
            for (int r = 0; r < 4; ++r) {
                int row = bm + wm + i * 16 + quad * 4 + r;
                int col = bn + wn + j * 16 + lrow;
                C[(size_t)row * K3_ + col] = acc[i][j][r] * inv;
            }
}

// ---------------------------------------------------------------- standalone scan (final chunk)
// R4-proven: 4 rolling 8-step register buffers, one wave per block.
__global__ __launch_bounds__(64, 1) void scan_kernel(const float* __restrict__ U,
                                                     const float* __restrict__ X,
                                                     const float* __restrict__ vf,
                                                     const float* __restrict__ vr,
                                                     const float* __restrict__ bfv,
                                                     const float* __restrict__ brv,
                                                     float* __restrict__ Y,
                                                     float* __restrict__ Cf,
                                                     float* __restrict__ carry,
                                                     int lenS, int s0) {
    int gid = blockIdx.x * 64 + threadIdx.x;   // 0..8191
    int b = gid >> 10;
    int h = gid & 1023;
    float vfh = vf[h], vrh = vr[h], bfh = bfv[h], brh = brv[h];
    const float* Ub = U + (size_t)b * lenS * K3_ + h;
    const float* Xb = X + ((size_t)b * S_ + s0) * H_ + h;
    float* Yb = Y + ((size_t)b * S_ + s0) * H_ + h;
    float c = carry[gid];

    float Af[8], Ac[8], Ar[8], Ax[8];
    float Bf[8], Bc[8], Br[8], Bx[8];
    float Cg[8], Cc[8], Cr[8], Cx[8];
    float Df[8], Dc[8], Dr[8], Dx[8];

    auto LOAD = [&](int t0, float (&sf)[8], float (&sc)[8], float (&sr)[8], float (&sx)[8]) {
#pragma unroll
        for (int u = 0; u < 8; ++u) {
            size_t o = (size_t)(t0 + u) * K3_;
            sf[u] = Ub[o];
            sc[u] = Ub[o + H_];
            sr[u] = Ub[o + 2 * H_];
            sx[u] = Xb[(size_t)(t0 + u) * H_];
        }
    };
    auto COMP = [&](int t0, float (&sf)[8], float (&sc)[8], float (&sr)[8], float (&sx)[8]) {
#pragma unroll
        for (int u = 0; u < 8; ++u) {
            float zf = sf[u] + bfh + vfh * c;
            float zr = sr[u] + brh + vrh * c;
            float xc = sc[u];
            float ft = __builtin_amdgcn_rcpf(1.f + __expf(-zf));
            float rt = __builtin_amdgcn_rcpf(1.f + __expf(-zr));
            c = ft * (c - xc) + xc;
            float xv = sx[u];
            float ht = rt * (c - xv) + xv;
            Yb[(size_t)(t0 + u) * H_] = ht;
        }
    };

    LOAD(0, Af, Ac, Ar, Ax);
    LOAD(8, Bf, Bc, Br, Bx);
    LOAD(16, Cg, Cc, Cr, Cx);
    for (int t0 = 0; t0 < lenS; t0 += 32) {
        LOAD(t0 + 24, Df, Dc, Dr, Dx);
        COMP(t0, Af, Ac, Ar, Ax);
        if (t0 + 32 < lenS) LOAD(t0 + 32, Af, Ac, Ar, Ax);
        COMP(t0 + 8, Bf, Bc, Br, Bx);
        if (t0 + 40 < lenS) LOAD(t0 + 40, Bf, Bc, Br, Bx);
        COMP(t0 + 16, Cg, Cc, Cr, Cx);
        if (t0 + 48 < lenS) LOAD(t0 + 48, Cg, Cc, Cr, Cx);
        COMP(t0 + 24, Df, Dc, Dr, Dx);
    }
    Cf[(size_t)b * H_ + h] = c;
}

// ---------------------------------------------------------------- launcher
extern "C" void kernel_launch(void* const* d_in, const int* in_sizes, int n_in,
                              void* d_out, int out_size, void* d_ws, size_t ws_size,
                              hipStream_t stream) {
    const float* x  = (const float*)d_in[0];
    const float* W  = (const float*)d_in[1];
    const float* vf = (const float*)d_in[2];
    const float* vr = (const float*)d_in[3];
    const float* bf = (const float*)d_in[4];
    const float* br = (const float*)d_in[5];
    float* y  = (float*)d_out;
    float* cf = y + (size_t)B_ * S_ * H_;

    // ws layout (bytes):
    //   U0 @0            50,331,648
    //   U1 @50,331,648   50,331,648
    //   xh0 @100,663,296  8,388,608
    //   xl0 @109,051,904  8,388,608
    //   Wth @117,440,512  6,291,456
    //   Wtl @123,731,968  6,291,456
    //   carry @130,023,424   32,768   (end 130,056,192 = proven-safe R6 bound)
    //   xh1 @130,056,192  8,388,608   (optional, big-ws only)
    //   xl1 @138,444,800  8,388,608   (end 146,833,408)
    char* base = (char*)d_ws;
    float* U0 = (float*)base;
    float* U1 = (float*)(base + 50331648);
    _Float16* xh0 = (_Float16*)(base + 100663296);
    _Float16* xl0 = (_Float16*)(base + 109051904);
    _Float16* Wth = (_Float16*)(base + 117440512);
    _Float16* Wtl = (_Float16*)(base + 123731968);
    float* carry  = (float*)(base + 130023424);
    _Float16* xh1 = (_Float16*)(base + 130056192);
    _Float16* xl1 = (_Float16*)(base + 138444800);

    const bool big = ws_size >= 146833408ULL;      // constant across calls -> graph-safe
    float* Ubuf[2] = {U0, U1};
    _Float16* Xh[2] = {xh0, big ? xh1 : xh0};
    _Float16* Xl[2] = {xl0, big ? xl1 : xl0};

    // chunk schedule: lens sum to 2048
    const int lens[5] = {512, 512, 512, 256, 256};
    const int lcls[5] = {9, 9, 9, 8, 8};
    const int s0s[5]  = {0, 512, 1024, 1536, 1792};

    // prep: transW + cast chunk0 into xbuf0
    prep_kernel<<<3072 + 1024, 256, 0, stream>>>(W, Wth, Wtl, (const float4*)x,
                                                 (f16x4*)xh0, (f16x4*)xl0);

    for (int i = 0; i < 5; ++i) {
        const int nGemm = (B_ * lens[i] / 128) * 24;
        const int nScan = (i >= 1) ? 32 : 0;
        int nCast = 0, lclC = 0, s0C = 0, nxt = 0;
        if (big && i < 4) {
            nxt   = i + 1;
            nCast = 2 * lens[nxt];                 // (B_*len*H_/16)/256
            lclC  = lcls[nxt];
            s0C   = s0s[nxt];
        } else if (!big && i >= 1) {
            // fallback: cast chunk i into xbuf0 right before its GEMM
            castx_kernel<<<2 * lens[i], 256, 0, stream>>>((const float4*)x, (f16x4*)xh0,
                                                          (f16x4*)xl0, lcls[i], s0s[i]);
        }
        const _Float16* Ah = Xh[big ? (i & 1) : 0];
        const _Float16* Al = Xl[big ? (i & 1) : 0];
        fused_kernel<<<nScan + nGemm + nCast, 256, 0, stream>>>(
            Ah, Al, Wth, Wtl, Ubuf[i & 1], nGemm,
            (i >= 1) ? Ubuf[(i - 1) & 1] : Ubuf[0],
            (i >= 1) ? lens[i - 1] : 0,
            (i >= 1) ? s0s[i - 1] : 0, nScan,
            x, (f16x4*)Xh[nxt & 1], (f16x4*)Xl[nxt & 1], lclC, s0C, nCast,
            vf, vr, bf, br, y, carry);
    }

    // final scan: chunk 4 (256 steps), writes Cf
    scan_kernel<<<B_ * H_ / 64, 64, 0, stream>>>(Ubuf[4 & 1], x, vf, vr, bf, br, y, cf, carry,
                                                 lens[4], s0s[4]);
}

// Round 8
// 570.177 us; speedup vs baseline: 1.3655x; 1.0091x over previous
//
#include <hip/hip_runtime.h>
#include <cstdint>
#include <cstddef>

#define B_   8
#define S_   2048
#define H_   1024
#define K3_  3072              // 3*H
#define SC_  512               // chunk length (uniform: only len=512 gives a balanced GEMM grid)
#define WSCALE 32.0f           // pre-scale W so f16 lo-plane stays normal-range

typedef __attribute__((ext_vector_type(8))) _Float16 f16x8;
typedef __attribute__((ext_vector_type(4))) _Float16 f16x4;
typedef __attribute__((ext_vector_type(4))) float f32x4;

// --------------------------------------------- cast body: x time-slice -> f16 hi/lo planes
// each thread converts 4 float4s
__device__ __forceinline__ void cast_body(const float4* __restrict__ X,
                                          f16x4* __restrict__ Xh, f16x4* __restrict__ Xl,
                                          int ci, int tid, int s0) {
    const int nthr = (B_ * SC_ * H_) >> 4;     // threads in cast range (4 float4 each)
    int i0 = ci * 256 + tid;
#pragma unroll
    for (int u = 0; u < 4; ++u) {
        int i  = i0 + u * nthr;
        int r  = i >> 8;                       // chunk-local row
        int c4 = i & 255;
        int b  = r >> 9;
        int sl = r & (SC_ - 1);
        size_t src = ((size_t)b * S_ + s0 + sl) * (H_ / 4) + c4;
        float4 v = X[src];
        _Float16 h0 = (_Float16)v.x, h1 = (_Float16)v.y, h2 = (_Float16)v.z, h3 = (_Float16)v.w;
        f16x4 hv = {h0, h1, h2, h3};
        f16x4 lv = {(_Float16)(v.x - (float)h0), (_Float16)(v.y - (float)h1),
                    (_Float16)(v.z - (float)h2), (_Float16)(v.w - (float)h3)};
        size_t dst = ((size_t)b * SC_ + sl) * (H_ / 4) + c4;
        Xh[dst] = hv;
        Xl[dst] = lv;
    }
}

// --------------------------------------------- standalone cast (small-ws fallback path)
__global__ __launch_bounds__(256) void castx_kernel(const float4* __restrict__ X,
                                                    f16x4* __restrict__ Xh,
                                                    f16x4* __restrict__ Xl, int s0) {
    cast_body(X, Xh, Xl, blockIdx.x, threadIdx.x, s0);
}

// --------------------------------------------- prep: transW (blocks 0..3071) + cast chunk0
__global__ __launch_bounds__(256) void prep_kernel(const float* __restrict__ W,
                                                   _Float16* __restrict__ Wth,
                                                   _Float16* __restrict__ Wtl,
                                                   const float4* __restrict__ X,
                                                   f16x4* __restrict__ Xh,
                                                   f16x4* __restrict__ Xl) {
    __shared__ float tile[32][33];
    if ((int)blockIdx.x < 3072) {
        int idx = blockIdx.x;
        int bc  = (idx % 96) * 32;         // col block in W (N dim)
        int brr = (idx / 96) * 32;         // row block in W (K dim)
        int tx = threadIdx.x & 31;
        int ty = threadIdx.x >> 5;
#pragma unroll
        for (int i = 0; i < 4; ++i) {
            int r = ty + i * 8;
            tile[r][tx] = W[(size_t)(brr + r) * K3_ + bc + tx];
        }
        __syncthreads();
#pragma unroll
        for (int i = 0; i < 4; ++i) {
            int r = ty + i * 8;            // row in Wt tile = col in W
            float v = tile[tx][r] * WSCALE;
            _Float16 h = (_Float16)v;
            _Float16 l = (_Float16)(v - (float)h);
            Wth[(size_t)(bc + r) * H_ + brr + tx] = h;
            Wtl[(size_t)(bc + r) * H_ + brr + tx] = l;
        }
    } else {
        cast_body(X, Xh, Xl, (int)blockIdx.x - 3072, threadIdx.x, 0);
    }
}

// ---------------------------------------------------------------- fused GEMM + scan + cast
// Blocks [0,nScan): scan of PREVIOUS chunk from Uprev (no barriers, waves independent).
// Blocks [nScan, nScan+nGemm): split-f16 3-term MFMA GEMM for CURRENT chunk -> C.
// Blocks [nScan+nGemm, +nCast): cast of NEXT chunk's x slice into the other x buffer.
__global__ __launch_bounds__(256) void fused_kernel(
        const _Float16* __restrict__ Ah, const _Float16* __restrict__ Al,
        const _Float16* __restrict__ Bh, const _Float16* __restrict__ Bl,
        float* __restrict__ C, int nGemm,
        const float* __restrict__ Uprev, int s0scan, int nScan,
        const float* __restrict__ X,
        f16x4* __restrict__ Xch, f16x4* __restrict__ Xcl, int s0cast,
        const float* __restrict__ vf,  const float* __restrict__ vr,
        const float* __restrict__ bfv, const float* __restrict__ brv,
        float* __restrict__ Y, float* __restrict__ carry) {
    __shared__ _Float16 Ahs[128 * 32];
    __shared__ _Float16 Als[128 * 32];
    __shared__ _Float16 Bhs[128 * 32];
    __shared__ _Float16 Bls[128 * 32];

    if ((int)blockIdx.x < nScan) {
        // ---------------- scan path (previous chunk), hidden under the GEMM ----------------
        int gid = blockIdx.x * 256 + threadIdx.x;   // 0..8191 channel
        int b = gid >> 10;
        int h = gid & 1023;
        float vfh = vf[h], vrh = vr[h], bfh = bfv[h], brh = brv[h];
        const float* Ub = Uprev + (size_t)b * SC_ * K3_ + h;
        const float* Xb = X + ((size_t)b * S_ + s0scan) * H_ + h;
        float* Yb = Y + ((size_t)b * S_ + s0scan) * H_ + h;
        float c = (s0scan == 0) ? 0.f : carry[gid];

        float Af[8], Ac[8], Ar[8], Ax[8];
        float Bf[8], Bc[8], Br[8], Bx[8];
        auto LOAD = [&](int t0, float (&sf)[8], float (&sc)[8], float (&sr)[8], float (&sx)[8]) {
#pragma unroll
            for (int u = 0; u < 8; ++u) {
                size_t o = (size_t)(t0 + u) * K3_;
                sf[u] = Ub[o];
                sc[u] = Ub[o + H_];
                sr[u] = Ub[o + 2 * H_];
                sx[u] = Xb[(size_t)(t0 + u) * H_];
            }
        };
        auto COMP = [&](int t0, float (&sf)[8], float (&sc)[8], float (&sr)[8], float (&sx)[8]) {
#pragma unroll
            for (int u = 0; u < 8; ++u) {
                float zf = sf[u] + bfh + vfh * c;
                float zr = sr[u] + brh + vrh * c;
                float xc = sc[u];
                float ft = __builtin_amdgcn_rcpf(1.f + __expf(-zf));
                float rt = __builtin_amdgcn_rcpf(1.f + __expf(-zr));
                c = ft * (c - xc) + xc;
                float xv = sx[u];
                float ht = rt * (c - xv) + xv;
                Yb[(size_t)(t0 + u) * H_] = ht;
            }
        };
        LOAD(0, Af, Ac, Ar, Ax);
        for (int t0 = 0; t0 < SC_; t0 += 16) {
            LOAD(t0 + 8, Bf, Bc, Br, Bx);
            COMP(t0, Af, Ac, Ar, Ax);
            if (t0 + 16 < SC_) LOAD(t0 + 16, Af, Ac, Ar, Ax);
            COMP(t0 + 8, Bf, Bc, Br, Bx);
        }
        carry[gid] = c;
        return;
    }

    if ((int)blockIdx.x >= nScan + nGemm) {
        // ---------------- cast path (next chunk), hidden under the GEMM ----------------
        cast_body((const float4*)X, Xch, Xcl, (int)blockIdx.x - nScan - nGemm,
                  threadIdx.x, s0cast);
        return;
    }

    // ---------------- GEMM path: U[m,n] = (1/WSCALE) * (AhBh + AhBl + AlBh) ----------------
    const int idxg = (int)blockIdx.x - nScan;
    const int bm   = (idxg / 24) * 128;
    const int bn   = (idxg % 24) * 128;
    const int tid  = threadIdx.x;
    const int lane = tid & 63;
    const int w    = tid >> 6;
    const int wm   = (w >> 1) * 64;
    const int wn   = (w & 1) * 64;
    const int K    = 1024;

    f32x4 acc[4][4];
#pragma unroll
    for (int i = 0; i < 4; ++i)
#pragma unroll
        for (int j = 0; j < 4; ++j) {
            f32x4 z = {0.f, 0.f, 0.f, 0.f};
            acc[i][j] = z;
        }

    const int quad = lane >> 4;
    const int lrow = lane & 15;

    for (int kk = 0; kk < K; kk += 32) {
#pragma unroll
        for (int j = 0; j < 2; ++j) {
            int idx = j * 256 + tid;          // 0..511
            int row = idx >> 2;
            int kp  = (idx & 3) << 3;
            size_t aoff = (size_t)(bm + row) * K + kk + kp;
            size_t boff = (size_t)(bn + row) * K + kk + kp;
            unsigned base = (unsigned)(j * 256 + (tid & ~63)) * 16u;  // wave-uniform bytes
            __builtin_amdgcn_global_load_lds(
                (const __attribute__((address_space(1))) void*)(Ah + aoff),
                (__attribute__((address_space(3))) void*)((char*)Ahs + base), 16, 0, 0);
            __builtin_amdgcn_global_load_lds(
                (const __attribute__((address_space(1))) void*)(Al + aoff),
                (__attribute__((address_space(3))) void*)((char*)Als + base), 16, 0, 0);
            __builtin_amdgcn_global_load_lds(
                (const __attribute__((address_space(1))) void*)(Bh + boff),
                (__attribute__((address_space(3))) void*)((char*)Bhs + base), 16, 0, 0);
            __builtin_amdgcn_global_load_lds(
                (const __attribute__((address_space(1))) void*)(Bl + boff),
                (__attribute__((address_space(3))) void*)((char*)Bls + base), 16, 0, 0);
        }
        __syncthreads();

        f16x8 ah[4], al[4], bh[4], bl[4];
#pragma unroll
        for (int i = 0; i < 4; ++i) {
            ah[i] = *(const f16x8*)(Ahs + (wm + i * 16 + lrow) * 32 + quad * 8);
            al[i] = *(const f16x8*)(Als + (wm + i * 16 + lrow) * 32 + quad * 8);
        }
#pragma unroll
        for (int j = 0; j < 4; ++j) {
            bh[j] = *(const f16x8*)(Bhs + (wn + j * 16 + lrow) * 32 + quad * 8);
            bl[j] = *(const f16x8*)(Bls + (wn + j * 16 + lrow) * 32 + quad * 8);
        }

#pragma unroll
        for (int i = 0; i < 4; ++i)
#pragma unroll
            for (int j = 0; j < 4; ++j) {
                acc[i][j] = __builtin_amdgcn_mfma_f32_16x16x32_f16(al[i], bh[j], acc[i][j], 0, 0, 0);
                acc[i][j] = __builtin_amdgcn_mfma_f32_16x16x32_f16(ah[i], bl[j], acc[i][j], 0, 0, 0);
                acc[i][j] = __builtin_amdgcn_mfma_f32_16x16x32_f16(ah[i], bh[j], acc[i][j], 0, 0, 0);
            }
        __syncthreads();
    }

    const float inv = 1.0f / WSCALE;
#pragma unroll
    for (int i = 0; i < 4; ++i)
#pragma unroll
        for (int j = 0; j < 4; ++j)
#pragma unroll
            for (int r = 0; r < 4; ++r) {
                int row = bm + wm + i * 16 + quad * 4 + r;
                int col = bn + wn + j * 16 + lrow;
                C[(size_t)row * K3_ + col] = acc[i][j][r] * inv;
            }
}

// ---------------------------------------------------------------- standalone scan (final chunk)
// 256 blocks x 32 active lanes: every CU gets a wave (vs 128 before) — halves per-wave
// channel count to probe CU-latency vs wave-issue bound. 4 rolling 8-step buffers.
__global__ __launch_bounds__(64, 1) void scan_final_kernel(const float* __restrict__ U,
                                                           const float* __restrict__ X,
                                                           const float* __restrict__ vf,
                                                           const float* __restrict__ vr,
                                                           const float* __restrict__ bfv,
                                                           const float* __restrict__ brv,
                                                           float* __restrict__ Y,
                                                           float* __restrict__ Cf,
                                                           const float* __restrict__ carry,
                                                           int s0) {
    int lane = threadIdx.x;
    if (lane >= 32) return;                    // half-wave idle; 256 blocks cover 8192 ch
    int gid = blockIdx.x * 32 + lane;          // 0..8191
    int b = gid >> 10;
    int h = gid & 1023;
    float vfh = vf[h], vrh = vr[h], bfh = bfv[h], brh = brv[h];
    const float* Ub = U + (size_t)b * SC_ * K3_ + h;
    const float* Xb = X + ((size_t)b * S_ + s0) * H_ + h;
    float* Yb = Y + ((size_t)b * S_ + s0) * H_ + h;
    float c = carry[gid];

    float Af[8], Ac[8], Ar[8], Ax[8];
    float Bf[8], Bc[8], Br[8], Bx[8];
    float Cg[8], Cc[8], Cr[8], Cx[8];
    float Df[8], Dc[8], Dr[8], Dx[8];

    auto LOAD = [&](int t0, float (&sf)[8], float (&sc)[8], float (&sr)[8], float (&sx)[8]) {
#pragma unroll
        for (int u = 0; u < 8; ++u) {
            size_t o = (size_t)(t0 + u) * K3_;
            sf[u] = Ub[o];
            sc[u] = Ub[o + H_];
            sr[u] = Ub[o + 2 * H_];
            sx[u] = Xb[(size_t)(t0 + u) * H_];
        }
    };
    auto COMP = [&](int t0, float (&sf)[8], float (&sc)[8], float (&sr)[8], float (&sx)[8]) {
#pragma unroll
        for (int u = 0; u < 8; ++u) {
            float zf = sf[u] + bfh + vfh * c;
            float zr = sr[u] + brh + vrh * c;
            float xc = sc[u];
            float ft = __builtin_amdgcn_rcpf(1.f + __expf(-zf));
            float rt = __builtin_amdgcn_rcpf(1.f + __expf(-zr));
            c = ft * (c - xc) + xc;
            float xv = sx[u];
            float ht = rt * (c - xv) + xv;
            Yb[(size_t)(t0 + u) * H_] = ht;
        }
    };

    LOAD(0, Af, Ac, Ar, Ax);
    LOAD(8, Bf, Bc, Br, Bx);
    LOAD(16, Cg, Cc, Cr, Cx);
    for (int t0 = 0; t0 < SC_; t0 += 32) {
        LOAD(t0 + 24, Df, Dc, Dr, Dx);
        COMP(t0, Af, Ac, Ar, Ax);
        if (t0 + 32 < SC_) LOAD(t0 + 32, Af, Ac, Ar, Ax);
        COMP(t0 + 8, Bf, Bc, Br, Bx);
        if (t0 + 40 < SC_) LOAD(t0 + 40, Bf, Bc, Br, Bx);
        COMP(t0 + 16, Cg, Cc, Cr, Cx);
        if (t0 + 48 < SC_) LOAD(t0 + 48, Cg, Cc, Cr, Cx);
        COMP(t0 + 24, Df, Dc, Dr, Dx);
    }
    Cf[(size_t)b * H_ + h] = c;
}

// ---------------------------------------------------------------- launcher
extern "C" void kernel_launch(void* const* d_in, const int* in_sizes, int n_in,
                              void* d_out, int out_size, void* d_ws, size_t ws_size,
                              hipStream_t stream) {
    const float* x  = (const float*)d_in[0];
    const float* W  = (const float*)d_in[1];
    const float* vf = (const float*)d_in[2];
    const float* vr = (const float*)d_in[3];
    const float* bf = (const float*)d_in[4];
    const float* br = (const float*)d_in[5];
    float* y  = (float*)d_out;
    float* cf = y + (size_t)B_ * S_ * H_;

    // ws layout (bytes):
    //   U0 @0            50,331,648
    //   U1 @50,331,648   50,331,648
    //   xh0 @100,663,296  8,388,608
    //   xl0 @109,051,904  8,388,608
    //   Wth @117,440,512  6,291,456
    //   Wtl @123,731,968  6,291,456
    //   carry @130,023,424   32,768
    //   xh1 @130,056,192  8,388,608   (big-ws only)
    //   xl1 @138,444,800  8,388,608   (end 146,833,408 — confirmed available in R7)
    char* base = (char*)d_ws;
    float* U0 = (float*)base;
    float* U1 = (float*)(base + 50331648);
    _Float16* xh0 = (_Float16*)(base + 100663296);
    _Float16* xl0 = (_Float16*)(base + 109051904);
    _Float16* Wth = (_Float16*)(base + 117440512);
    _Float16* Wtl = (_Float16*)(base + 123731968);
    float* carry  = (float*)(base + 130023424);
    _Float16* xh1 = (_Float16*)(base + 130056192);
    _Float16* xl1 = (_Float16*)(base + 138444800);

    const bool big = ws_size >= 146833408ULL;      // constant across calls -> graph-safe
    float* Ubuf[2] = {U0, U1};
    _Float16* Xh[2] = {xh0, big ? xh1 : xh0};
    _Float16* Xl[2] = {xl0, big ? xl1 : xl0};

    // prep: transW + cast chunk0 into xbuf0
    prep_kernel<<<3072 + 1024, 256, 0, stream>>>(W, Wth, Wtl, (const float4*)x,
                                                 (f16x4*)xh0, (f16x4*)xl0);

    const int NGEMM = (B_ * SC_ / 128) * 24;       // 768 = 3 blocks/CU, balanced
    for (int i = 0; i < 4; ++i) {
        const int nScan = (i >= 1) ? 32 : 0;
        int nCast = 0, s0C = 0, nxt = i;
        if (big && i < 3) {
            nxt   = i + 1;
            nCast = 1024;                          // (B_*SC_*H_/16)/256
            s0C   = nxt * SC_;
        } else if (!big && i >= 1) {
            castx_kernel<<<1024, 256, 0, stream>>>((const float4*)x, (f16x4*)xh0,
                                                   (f16x4*)xl0, i * SC_);
        }
        const _Float16* Ah = Xh[big ? (i & 1) : 0];
        const _Float16* Al = Xl[big ? (i & 1) : 0];
        fused_kernel<<<nScan + NGEMM + nCast, 256, 0, stream>>>(
            Ah, Al, Wth, Wtl, Ubuf[i & 1], NGEMM,
            (i >= 1) ? Ubuf[(i - 1) & 1] : Ubuf[0],
            (i >= 1) ? (i - 1) * SC_ : 0, nScan,
            x, (f16x4*)Xh[nxt & 1], (f16x4*)Xl[nxt & 1], s0C,
            vf, vr, bf, br, y, carry);
    }

    // final scan: chunk 3, writes Cf — 256 blocks so every CU gets a wave
    scan_final_kernel<<<256, 64, 0, stream>>>(Ubuf[1], x, vf, vr, bf, br, y, cf, carry, 3 * SC_);
}